// Round 1
// baseline (331.052 us; speedup 1.0000x reference)
//
#include <hip/hip_runtime.h>
#include <hip/hip_bf16.h>

// PLE multi-task model, fused bf16-MFMA implementation.
// Expert order: e0,e1 = task1-specific; e2,e3 = task2-specific; e4,e5 = shared.
// Layer-1 GEMM: x[64tok,512] @ W1cat[512,400] (cols 0-383 experts, 384-391 gate logits, 392-399 zero pad)

#define MT 64          // tokens per block
#define NT1 25         // layer-1 N-tiles (24 expert + 1 gate/pad)

typedef __bf16 bf16x8 __attribute__((ext_vector_type(8)));
typedef float f32x4 __attribute__((ext_vector_type(4)));

__device__ __forceinline__ unsigned short f2bf(float f) {
    unsigned u = __builtin_bit_cast(unsigned, f);
    return (unsigned short)((u + 0x7FFFu + ((u >> 16) & 1u)) >> 16);
}

// ---------------- weight packing ----------------
// wf1[nt=25][ks=16][lane=64][j=8]: element W1cat[k = ks*32+(lane>>4)*8+j][col = nt*16+(lane&15)]
__global__ void pack_w1(const float* __restrict__ sh_W1, const float* __restrict__ t1_W1,
                        const float* __restrict__ t2_W1, const float* __restrict__ g1_W,
                        const float* __restrict__ g2_W, unsigned short* __restrict__ wf1) {
    int p = blockIdx.x * blockDim.x + threadIdx.x;
    if (p >= NT1 * 16 * 64 * 8) return;
    int j = p & 7, lane = (p >> 3) & 63, ks = (p >> 9) & 15, nt = p >> 13;
    int col = nt * 16 + (lane & 15);
    int k = ks * 32 + (lane >> 4) * 8 + j;
    float v = 0.f;
    if (col < 384) {
        int e = col >> 6, ci = col & 63;
        const float* W = (e < 2) ? t1_W1 : (e < 4) ? t2_W1 : sh_W1;
        v = W[((size_t)(e & 1) * 512 + k) * 64 + ci];
    } else if (col < 388) {
        v = g1_W[k * 4 + (col - 384)];
    } else if (col < 392) {
        v = g2_W[k * 4 + (col - 388)];
    }
    wf1[p] = f2bf(v);
}

// wf2[e][nt=2][ks=2][lane][8], wf3[e][nt=2][lane][8], plus packed biases
__global__ void pack_rest(const float* __restrict__ sh_W2, const float* __restrict__ t1_W2,
                          const float* __restrict__ t2_W2,
                          const float* __restrict__ sh_W3, const float* __restrict__ t1_W3,
                          const float* __restrict__ t2_W3,
                          const float* __restrict__ sh_b1, const float* __restrict__ t1_b1,
                          const float* __restrict__ t2_b1,
                          const float* __restrict__ sh_b2, const float* __restrict__ t1_b2,
                          const float* __restrict__ t2_b2,
                          const float* __restrict__ sh_b3, const float* __restrict__ t1_b3,
                          const float* __restrict__ t2_b3,
                          const float* __restrict__ g1_b, const float* __restrict__ g2_b,
                          unsigned short* __restrict__ wf2, unsigned short* __restrict__ wf3,
                          float* __restrict__ b1c, float* __restrict__ b2c, float* __restrict__ b3c) {
    int p = blockIdx.x * blockDim.x + threadIdx.x;
    if (p < 12288) {                       // wf2: 6*2*2*64*8
        int j = p & 7, lane = (p >> 3) & 63, ks = (p >> 9) & 1, nt = (p >> 10) & 1, e = p >> 11;
        int col = nt * 16 + (lane & 15);
        int k = ks * 32 + (lane >> 4) * 8 + j;
        const float* W = (e < 2) ? t1_W2 : (e < 4) ? t2_W2 : sh_W2;
        wf2[p] = f2bf(W[((size_t)(e & 1) * 64 + k) * 32 + col]);
    } else if (p < 18432) {                // wf3: 6*2*64*8
        int q = p - 12288;
        int j = q & 7, lane = (q >> 3) & 63, nt = (q >> 9) & 1, e = q >> 10;
        int col = nt * 16 + (lane & 15);
        int k = (lane >> 4) * 8 + j;
        const float* W = (e < 2) ? t1_W3 : (e < 4) ? t2_W3 : sh_W3;
        wf3[q] = f2bf(W[((size_t)(e & 1) * 32 + k) * 32 + col]);
    } else if (p < 18432 + 392) {          // b1c[392]: expert b1 (384) + g1_b(4) + g2_b(4)
        int t = p - 18432;
        float v;
        if (t < 384) {
            int e = t >> 6, ci = t & 63;
            const float* bb = (e < 2) ? t1_b1 : (e < 4) ? t2_b1 : sh_b1;
            v = bb[(e & 1) * 64 + ci];
        } else if (t < 388) v = g1_b[t - 384];
        else v = g2_b[t - 388];
        b1c[t] = v;
    } else if (p < 18824 + 192) {          // b2c[192]
        int t = p - 18824;
        int e = t >> 5, ci = t & 31;
        const float* bb = (e < 2) ? t1_b2 : (e < 4) ? t2_b2 : sh_b2;
        b2c[t] = bb[(e & 1) * 32 + ci];
    } else if (p < 19016 + 192) {          // b3c[192]
        int t = p - 19016;
        int e = t >> 5, ci = t & 31;
        const float* bb = (e < 2) ? t1_b3 : (e < 4) ? t2_b3 : sh_b3;
        b3c[t] = bb[(e & 1) * 32 + ci];
    }
}

// ---------------- fused main kernel ----------------
// LDS map (bytes):
//   [0,      66560)  xlds  [64][520] bf16   (later: g1l f32 [64][34] at +4096)
//   [66560, 116736)  h1    [64][392] bf16   / eo f32 [6][64][32] / th2 f32 [64][66]
//   [116736,142336)  h2    [64][200] bf16   / g2l f32 [64][34] @+0, th1 f32 [64][66] @+8704
//   [142336,144384)  gate  [64][8] f32
//   [144384,146432)  sel   [64][8] f32
#define LDS_BYTES 146432

__global__ __launch_bounds__(512, 2) void ple_fused(
    const float* __restrict__ x,
    const unsigned short* __restrict__ wf1, const unsigned short* __restrict__ wf2,
    const unsigned short* __restrict__ wf3,
    const float* __restrict__ b1c, const float* __restrict__ b2c, const float* __restrict__ b3c,
    const float* __restrict__ tw1_W1, const float* __restrict__ tw1_b1,
    const float* __restrict__ tw1_W2, const float* __restrict__ tw1_b2,
    const float* __restrict__ tw2_W1, const float* __restrict__ tw2_b1,
    const float* __restrict__ tw2_W2, const float* __restrict__ tw2_b2,
    float* __restrict__ out, int ntok) {
    extern __shared__ char smem[];
    unsigned short* xlds = (unsigned short*)smem;              // [64][520]
    float* g1l = (float*)(smem + 4096);                        // [64][34]
    unsigned short* h1 = (unsigned short*)(smem + 66560);      // [64][392]
    float* eo = (float*)(smem + 66560);                        // [6][64][32]
    float* th2 = (float*)(smem + 66560);                       // [64][66]
    unsigned short* h2 = (unsigned short*)(smem + 116736);     // [64][200]
    float* g2l = (float*)(smem + 116736);                      // [64][34]
    float* th1 = (float*)(smem + 125440);                      // [64][66]
    float* gate = (float*)(smem + 142336);                     // [64][8]
    float* sel = (float*)(smem + 144384);                      // [64][8]

    const int tid = threadIdx.x;
    const int w = tid >> 6, l = tid & 63, r = l & 15, g = l >> 4;
    const int tok0 = blockIdx.x * MT;

    // ---- phase 1: stage x tile (64 tok x 512) fp32 -> bf16 LDS ----
    const float* xb = x + (size_t)tok0 * 512;
#pragma unroll
    for (int i = 0; i < 16; ++i) {
        int f = i * 2048 + tid * 4;
        const float4 v = *(const float4*)(xb + f);
        int tok = f >> 9, k = f & 511;
        unsigned lo = (unsigned)f2bf(v.x) | ((unsigned)f2bf(v.y) << 16);
        unsigned hi = (unsigned)f2bf(v.z) | ((unsigned)f2bf(v.w) << 16);
        *(uint2*)(&xlds[tok * 520 + k]) = make_uint2(lo, hi);
    }
    __syncthreads();

    // ---- phase 2: layer-1 GEMM (M=64,N=400,K=512), barrier-free K-loop ----
    int ntl[4] = {w, w + 8, w + 16, 24};
    const int ntn = (w == 7) ? 4 : 3;

    f32x4 acc[4][4];
#pragma unroll
    for (int i = 0; i < 4; ++i)
#pragma unroll
        for (int m = 0; m < 4; ++m) acc[i][m] = (f32x4){0.f, 0.f, 0.f, 0.f};

    const bf16x8* wf1v = (const bf16x8*)wf1;
#pragma unroll 4
    for (int ks = 0; ks < 16; ++ks) {
        bf16x8 bfr[4];
#pragma unroll
        for (int i = 0; i < 4; ++i)
            if (i < ntn) bfr[i] = wf1v[((ntl[i] * 16 + ks) << 6) + l];
        bf16x8 afr[4];
#pragma unroll
        for (int m = 0; m < 4; ++m)
            afr[m] = *(const bf16x8*)&xlds[(m * 16 + r) * 520 + ks * 32 + g * 8];
#pragma unroll
        for (int i = 0; i < 4; ++i)
            if (i < ntn)
#pragma unroll
                for (int m = 0; m < 4; ++m)
                    acc[i][m] = __builtin_amdgcn_mfma_f32_16x16x32_bf16(afr[m], bfr[i], acc[i][m], 0, 0, 0);
    }

    // epilogue 1: bias+relu -> h1 (bf16); gate logits -> gate
#pragma unroll
    for (int i = 0; i < 4; ++i)
        if (i < ntn) {
            int nt = ntl[i];
            if (nt < 24) {
#pragma unroll
                for (int m = 0; m < 4; ++m)
#pragma unroll
                    for (int q = 0; q < 4; ++q) {
                        int tokr = m * 16 + g * 4 + q;
                        int col = nt * 16 + r;
                        float v = acc[i][m][q] + b1c[col];
                        h1[tokr * 392 + col] = f2bf(fmaxf(v, 0.f));
                    }
            } else if (r < 8) {
#pragma unroll
                for (int m = 0; m < 4; ++m)
#pragma unroll
                    for (int q = 0; q < 4; ++q) {
                        int tokr = m * 16 + g * 4 + q;
                        gate[tokr * 8 + r] = acc[i][m][q] + b1c[384 + r];
                    }
            }
        }
    __syncthreads();

    // ---- phase 3: gate softmax (wave0 lanes) + layer-2 ----
    if (tid < 64) {
#pragma unroll
        for (int gi = 0; gi < 2; ++gi) {
            float l0 = gate[tid * 8 + gi * 4 + 0];
            float l1 = gate[tid * 8 + gi * 4 + 1];
            float l2 = gate[tid * 8 + gi * 4 + 2];
            float l3 = gate[tid * 8 + gi * 4 + 3];
            float mx = fmaxf(fmaxf(l0, l1), fmaxf(l2, l3));
            float e0 = __expf(l0 - mx), e1 = __expf(l1 - mx);
            float e2 = __expf(l2 - mx), e3 = __expf(l3 - mx);
            float inv = 1.f / (e0 + e1 + e2 + e3);
            sel[tid * 8 + gi * 4 + 0] = e0 * inv;
            sel[tid * 8 + gi * 4 + 1] = e1 * inv;
            sel[tid * 8 + gi * 4 + 2] = e2 * inv;
            sel[tid * 8 + gi * 4 + 3] = e3 * inv;
        }
    }

    // jobs: j in [0,12): e=j>>1, nt2=j&1. wave w -> job w; waves 0-3 also job w+8.
    const int nj = (w < 4) ? 2 : 1;
    const int je[2] = {w >> 1, (w + 8) >> 1};
    const int jn[2] = {w & 1, w & 1};

    f32x4 acc2[2][4];
#pragma unroll
    for (int jj = 0; jj < 2; ++jj)
#pragma unroll
        for (int m = 0; m < 4; ++m) acc2[jj][m] = (f32x4){0.f, 0.f, 0.f, 0.f};

    const bf16x8* wf2v = (const bf16x8*)wf2;
#pragma unroll
    for (int jj = 0; jj < 2; ++jj)
        if (jj < nj) {
            int e = je[jj], nt2 = jn[jj];
#pragma unroll
            for (int ks = 0; ks < 2; ++ks) {
                bf16x8 bb = wf2v[(((e * 2 + nt2) * 2 + ks) << 6) + l];
#pragma unroll
                for (int m = 0; m < 4; ++m) {
                    bf16x8 aa = *(const bf16x8*)&h1[(m * 16 + r) * 392 + e * 64 + ks * 32 + g * 8];
                    acc2[jj][m] = __builtin_amdgcn_mfma_f32_16x16x32_bf16(aa, bb, acc2[jj][m], 0, 0, 0);
                }
            }
        }
#pragma unroll
    for (int jj = 0; jj < 2; ++jj)
        if (jj < nj) {
            int e = je[jj], nt2 = jn[jj];
#pragma unroll
            for (int m = 0; m < 4; ++m)
#pragma unroll
                for (int q = 0; q < 4; ++q) {
                    int tokr = m * 16 + g * 4 + q;
                    int col = nt2 * 16 + r;
                    float v = acc2[jj][m][q] + b2c[e * 32 + col];
                    h2[tokr * 200 + e * 32 + col] = f2bf(fmaxf(v, 0.f));
                }
        }
    __syncthreads();

    // ---- phase 4: layer-3 -> eo (f32, aliases h1 region; h1 dead) ----
    f32x4 acc3[2][4];
#pragma unroll
    for (int jj = 0; jj < 2; ++jj)
#pragma unroll
        for (int m = 0; m < 4; ++m) acc3[jj][m] = (f32x4){0.f, 0.f, 0.f, 0.f};

    const bf16x8* wf3v = (const bf16x8*)wf3;
#pragma unroll
    for (int jj = 0; jj < 2; ++jj)
        if (jj < nj) {
            int e = je[jj], nt2 = jn[jj];
            bf16x8 bb = wf3v[((e * 2 + nt2) << 6) + l];
#pragma unroll
            for (int m = 0; m < 4; ++m) {
                bf16x8 aa = *(const bf16x8*)&h2[(m * 16 + r) * 200 + e * 32 + g * 8];
                acc3[jj][m] = __builtin_amdgcn_mfma_f32_16x16x32_bf16(aa, bb, acc3[jj][m], 0, 0, 0);
            }
        }
#pragma unroll
    for (int jj = 0; jj < 2; ++jj)
        if (jj < nj) {
            int e = je[jj], nt2 = jn[jj];
#pragma unroll
            for (int m = 0; m < 4; ++m)
#pragma unroll
                for (int q = 0; q < 4; ++q) {
                    int tokr = m * 16 + g * 4 + q;
                    eo[((size_t)e * 64 + tokr) * 32 + nt2 * 16 + r] =
                        acc3[jj][m][q] + b3c[e * 32 + nt2 * 16 + r];
                }
        }
    __syncthreads();

    // ---- phase 5: gated mixing -> g1l, g2l ----
    {
        int tok = tid >> 3, c0 = (tid & 7) * 4;
        float s[8];
#pragma unroll
        for (int i = 0; i < 8; ++i) s[i] = sel[tok * 8 + i];
#pragma unroll
        for (int c = 0; c < 4; ++c) {
            int cc = c0 + c;
            float e0 = eo[((size_t)0 * 64 + tok) * 32 + cc];
            float e1 = eo[((size_t)1 * 64 + tok) * 32 + cc];
            float e2 = eo[((size_t)2 * 64 + tok) * 32 + cc];
            float e3 = eo[((size_t)3 * 64 + tok) * 32 + cc];
            float e4 = eo[((size_t)4 * 64 + tok) * 32 + cc];
            float e5 = eo[((size_t)5 * 64 + tok) * 32 + cc];
            // task1 mix order: [t1_0, t1_1, sh_0, sh_1] ; task2: [t2_0, t2_1, sh_0, sh_1]
            g1l[tok * 34 + cc] = s[0] * e0 + s[1] * e1 + s[2] * e4 + s[3] * e5;
            g2l[tok * 34 + cc] = s[4] * e2 + s[5] * e3 + s[6] * e4 + s[7] * e5;
        }
    }
    __syncthreads();

    // ---- phase 6: tower hidden layers (both towers) ----
    {
        int tok = tid >> 3, h0 = (tid & 7) * 8;
        float a1[8], a2[8];
#pragma unroll
        for (int hh = 0; hh < 8; ++hh) {
            a1[hh] = tw1_b1[h0 + hh];
            a2[hh] = tw2_b1[h0 + hh];
        }
        for (int c = 0; c < 32; ++c) {
            float gv1 = g1l[tok * 34 + c], gv2 = g2l[tok * 34 + c];
#pragma unroll
            for (int hh = 0; hh < 8; ++hh) {
                a1[hh] += gv1 * tw1_W1[c * 64 + h0 + hh];
                a2[hh] += gv2 * tw2_W1[c * 64 + h0 + hh];
            }
        }
#pragma unroll
        for (int hh = 0; hh < 8; ++hh) {
            th1[tok * 66 + h0 + hh] = fmaxf(a1[hh], 0.f);
            th2[tok * 66 + h0 + hh] = fmaxf(a2[hh], 0.f);
        }
    }
    __syncthreads();

    // ---- phase 7: tower outputs ----
    if (tid < 192) {
        int tok = tid / 3, jx = tid % 3;
        float s = tw1_b2[jx];
        for (int hh = 0; hh < 64; ++hh) s += th1[tok * 66 + hh] * tw1_W2[hh * 3 + jx];
        if (jx != 1) s = 1.f / (1.f + __expf(-s));          // sigmoid cols 0,2
        out[(size_t)(tok0 + tok) * 3 + jx] = s;
    } else if (tid < 320) {
        int t2 = tid - 192, tok = t2 >> 1, jx = t2 & 1;
        float s = tw2_b2[jx];
        for (int hh = 0; hh < 64; ++hh) s += th2[tok * 66 + hh] * tw2_W2[hh * 2 + jx];
        if (jx == 1) s = 1.f / (1.f + __expf(-s));          // sigmoid col 1
        out[(size_t)ntok * 3 + (size_t)(tok0 + tok) * 2 + jx] = s;
    }
}

// ---------------- launcher ----------------
extern "C" void kernel_launch(void* const* d_in, const int* in_sizes, int n_in,
                              void* d_out, int out_size, void* d_ws, size_t ws_size,
                              hipStream_t stream) {
    const float* x = (const float*)d_in[0];
    const float* sh_W1 = (const float*)d_in[1];
    const float* sh_b1 = (const float*)d_in[2];
    const float* sh_W2 = (const float*)d_in[3];
    const float* sh_b2 = (const float*)d_in[4];
    const float* sh_W3 = (const float*)d_in[5];
    const float* sh_b3 = (const float*)d_in[6];
    const float* t1_W1 = (const float*)d_in[7];
    const float* t1_b1 = (const float*)d_in[8];
    const float* t1_W2 = (const float*)d_in[9];
    const float* t1_b2 = (const float*)d_in[10];
    const float* t1_W3 = (const float*)d_in[11];
    const float* t1_b3 = (const float*)d_in[12];
    const float* t2_W1 = (const float*)d_in[13];
    const float* t2_b1 = (const float*)d_in[14];
    const float* t2_W2 = (const float*)d_in[15];
    const float* t2_b2 = (const float*)d_in[16];
    const float* t2_W3 = (const float*)d_in[17];
    const float* t2_b3 = (const float*)d_in[18];
    const float* g1_W = (const float*)d_in[19];
    const float* g1_b = (const float*)d_in[20];
    const float* g2_W = (const float*)d_in[21];
    const float* g2_b = (const float*)d_in[22];
    const float* tw1_W1 = (const float*)d_in[23];
    const float* tw1_b1 = (const float*)d_in[24];
    const float* tw1_W2 = (const float*)d_in[25];
    const float* tw1_b2 = (const float*)d_in[26];
    const float* tw2_W1 = (const float*)d_in[27];
    const float* tw2_b1 = (const float*)d_in[28];
    const float* tw2_W2 = (const float*)d_in[29];
    const float* tw2_b2 = (const float*)d_in[30];

    // d_ws layout (bytes): wf1@0 (409600), wf2@409600 (24576), wf3@434176 (12288),
    //                      b1c@446464 (1568), b2c@448032 (768), b3c@448800 (768)
    unsigned short* wf1 = (unsigned short*)d_ws;
    unsigned short* wf2 = (unsigned short*)((char*)d_ws + 409600);
    unsigned short* wf3 = (unsigned short*)((char*)d_ws + 434176);
    float* b1c = (float*)((char*)d_ws + 446464);
    float* b2c = (float*)((char*)d_ws + 448032);
    float* b3c = (float*)((char*)d_ws + 448800);

    pack_w1<<<400, 512, 0, stream>>>(sh_W1, t1_W1, t2_W1, g1_W, g2_W, wf1);
    pack_rest<<<38, 512, 0, stream>>>(sh_W2, t1_W2, t2_W2, sh_W3, t1_W3, t2_W3,
                                      sh_b1, t1_b1, t2_b1, sh_b2, t1_b2, t2_b2,
                                      sh_b3, t1_b3, t2_b3, g1_b, g2_b,
                                      wf2, wf3, b1c, b2c, b3c);

    (void)hipFuncSetAttribute((const void*)ple_fused,
                              hipFuncAttributeMaxDynamicSharedMemorySize, LDS_BYTES);

    int ntok = in_sizes[0] / 512;
    int nblk = ntok / MT;
    ple_fused<<<nblk, 512, LDS_BYTES, stream>>>(
        x, wf1, wf2, wf3, b1c, b2c, b3c,
        tw1_W1, tw1_b1, tw1_W2, tw1_b2, tw2_W1, tw2_b1, tw2_W2, tw2_b2,
        (float*)d_out, ntok);
}

// Round 2
// 306.911 us; speedup vs baseline: 1.0787x; 1.0787x over previous
//
#include <hip/hip_runtime.h>
#include <hip/hip_bf16.h>

// PLE multi-task model, fused bf16-MFMA implementation. Round 2: MT=32,
// LDS 74.2KB -> 2 blocks/CU (occupancy was the round-1 bottleneck).
// Expert order: e0,e1 = task1-specific; e2,e3 = task2-specific; e4,e5 = shared.
// Layer-1 GEMM: x[32tok,512] @ W1cat[512,400] (cols 0-383 experts, 384-391 gate logits)

#define MT 32          // tokens per block
#define NT1 25         // layer-1 N-tiles (24 expert + 1 gate/pad)

typedef __bf16 bf16x8 __attribute__((ext_vector_type(8)));
typedef float f32x4 __attribute__((ext_vector_type(4)));

__device__ __forceinline__ unsigned short f2bf(float f) {
    unsigned u = __builtin_bit_cast(unsigned, f);
    return (unsigned short)((u + 0x7FFFu + ((u >> 16) & 1u)) >> 16);
}
__device__ __forceinline__ unsigned pk(float a, float b) {
    return (unsigned)f2bf(a) | ((unsigned)f2bf(b) << 16);
}

// ---------------- weight packing (single kernel) ----------------
// wf1[nt=25][ks=16][lane=64][j=8]: W1cat[k = ks*32+(lane>>4)*8+j][col = nt*16+(lane&15)]
// wf2[e][nt=2][ks=2][lane][8], wf3[e][nt=2][lane][8], packed biases b1c/b2c/b3c
__global__ void pack_all(const float* __restrict__ sh_W1, const float* __restrict__ t1_W1,
                         const float* __restrict__ t2_W1, const float* __restrict__ g1_W,
                         const float* __restrict__ g2_W,
                         const float* __restrict__ sh_W2, const float* __restrict__ t1_W2,
                         const float* __restrict__ t2_W2,
                         const float* __restrict__ sh_W3, const float* __restrict__ t1_W3,
                         const float* __restrict__ t2_W3,
                         const float* __restrict__ sh_b1, const float* __restrict__ t1_b1,
                         const float* __restrict__ t2_b1,
                         const float* __restrict__ sh_b2, const float* __restrict__ t1_b2,
                         const float* __restrict__ t2_b2,
                         const float* __restrict__ sh_b3, const float* __restrict__ t1_b3,
                         const float* __restrict__ t2_b3,
                         const float* __restrict__ g1_b, const float* __restrict__ g2_b,
                         unsigned short* __restrict__ wf1, unsigned short* __restrict__ wf2,
                         unsigned short* __restrict__ wf3,
                         float* __restrict__ b1c, float* __restrict__ b2c, float* __restrict__ b3c) {
    int p0 = blockIdx.x * blockDim.x + threadIdx.x;
    if (p0 < 204800) {                     // wf1: 25*16*64*8
        int p = p0;
        int j = p & 7, lane = (p >> 3) & 63, ks = (p >> 9) & 15, nt = p >> 13;
        int col = nt * 16 + (lane & 15);
        int k = ks * 32 + (lane >> 4) * 8 + j;
        float v = 0.f;
        if (col < 384) {
            int e = col >> 6, ci = col & 63;
            const float* W = (e < 2) ? t1_W1 : (e < 4) ? t2_W1 : sh_W1;
            v = W[((size_t)(e & 1) * 512 + k) * 64 + ci];
        } else if (col < 388) {
            v = g1_W[k * 4 + (col - 384)];
        } else if (col < 392) {
            v = g2_W[k * 4 + (col - 388)];
        }
        wf1[p] = f2bf(v);
        return;
    }
    int p = p0 - 204800;
    if (p < 12288) {                       // wf2: 6*2*2*64*8
        int j = p & 7, lane = (p >> 3) & 63, ks = (p >> 9) & 1, nt = (p >> 10) & 1, e = p >> 11;
        int col = nt * 16 + (lane & 15);
        int k = ks * 32 + (lane >> 4) * 8 + j;
        const float* W = (e < 2) ? t1_W2 : (e < 4) ? t2_W2 : sh_W2;
        wf2[p] = f2bf(W[((size_t)(e & 1) * 64 + k) * 32 + col]);
    } else if (p < 18432) {                // wf3: 6*2*64*8
        int q = p - 12288;
        int j = q & 7, lane = (q >> 3) & 63, nt = (q >> 9) & 1, e = q >> 10;
        int col = nt * 16 + (lane & 15);
        int k = (lane >> 4) * 8 + j;
        const float* W = (e < 2) ? t1_W3 : (e < 4) ? t2_W3 : sh_W3;
        wf3[q] = f2bf(W[((size_t)(e & 1) * 32 + k) * 32 + col]);
    } else if (p < 18432 + 392) {          // b1c[392]: expert b1 (384) + g1_b(4) + g2_b(4)
        int t = p - 18432;
        float v;
        if (t < 384) {
            int e = t >> 6, ci = t & 63;
            const float* bb = (e < 2) ? t1_b1 : (e < 4) ? t2_b1 : sh_b1;
            v = bb[(e & 1) * 64 + ci];
        } else if (t < 388) v = g1_b[t - 384];
        else v = g2_b[t - 388];
        b1c[t] = v;
    } else if (p < 18824 + 192) {          // b2c[192]
        int t = p - 18824;
        int e = t >> 5, ci = t & 31;
        const float* bb = (e < 2) ? t1_b2 : (e < 4) ? t2_b2 : sh_b2;
        b2c[t] = bb[(e & 1) * 32 + ci];
    } else if (p < 19016 + 192) {          // b3c[192]
        int t = p - 19016;
        int e = t >> 5, ci = t & 31;
        const float* bb = (e < 2) ? t1_b3 : (e < 4) ? t2_b3 : sh_b3;
        b3c[t] = bb[(e & 1) * 32 + ci];
    }
}

// ---------------- fused main kernel ----------------
// LDS map (bytes), MT=32:
//   [0,     33280)  xlds [32][520] bf16 ; after phase2 aliased:
//                     g1l f32 [32][33] @+0, g2l @+4224, th1 f32 [32][66] @+8448, th2 @+16896
//   [33280, 59392)  h1 [32][408] bf16 ; phase4+ aliased: eo f32 [6][32][33]
//   [59392, 72192)  h2 [32][200] bf16
//   [72192, 73216)  gate [32][8] f32
//   [73216, 74240)  sel  [32][8] f32
#define LDS_BYTES 74240

__global__ __launch_bounds__(512, 4) void ple_fused(
    const float* __restrict__ x,
    const unsigned short* __restrict__ wf1, const unsigned short* __restrict__ wf2,
    const unsigned short* __restrict__ wf3,
    const float* __restrict__ b1c, const float* __restrict__ b2c, const float* __restrict__ b3c,
    const float* __restrict__ tw1_W1, const float* __restrict__ tw1_b1,
    const float* __restrict__ tw1_W2, const float* __restrict__ tw1_b2,
    const float* __restrict__ tw2_W1, const float* __restrict__ tw2_b1,
    const float* __restrict__ tw2_W2, const float* __restrict__ tw2_b2,
    float* __restrict__ out, int ntok) {
    extern __shared__ char smem[];
    unsigned short* xlds = (unsigned short*)smem;              // [32][520]
    float* g1l = (float*)(smem + 0);                           // [32][33]
    float* g2l = (float*)(smem + 4224);                        // [32][33]
    float* th1 = (float*)(smem + 8448);                        // [32][66]
    float* th2 = (float*)(smem + 16896);                       // [32][66]
    unsigned short* h1 = (unsigned short*)(smem + 33280);      // [32][408]
    float* eo = (float*)(smem + 33280);                        // [6][32][33]
    unsigned short* h2 = (unsigned short*)(smem + 59392);      // [32][200]
    float* gate = (float*)(smem + 72192);                      // [32][8]
    float* sel = (float*)(smem + 73216);                       // [32][8]

    const int tid = threadIdx.x;
    const int w = tid >> 6, l = tid & 63, r = l & 15, g = l >> 4;
    const int tok0 = blockIdx.x * MT;

    // ---- phase 1: stage x tile (32 tok x 512) fp32 -> bf16 LDS, 16B stores ----
    const float* xb = x + (size_t)tok0 * 512;
#pragma unroll
    for (int i = 0; i < 4; ++i) {
        int f = i * 4096 + tid * 8;
        const float4 a = *(const float4*)(xb + f);
        const float4 b = *(const float4*)(xb + f + 4);
        int tok = f >> 9, k = f & 511;
        uint4 u = make_uint4(pk(a.x, a.y), pk(a.z, a.w), pk(b.x, b.y), pk(b.z, b.w));
        *(uint4*)(&xlds[tok * 520 + k]) = u;
    }
    __syncthreads();

    // ---- phase 2: layer-1 GEMM (M=32,N=400,K=512), barrier-free K-loop ----
    int ntl[4] = {w, w + 8, w + 16, 24};
    const int ntn = (w == 7) ? 4 : 3;

    f32x4 acc[4][2];
#pragma unroll
    for (int i = 0; i < 4; ++i)
#pragma unroll
        for (int m = 0; m < 2; ++m) acc[i][m] = (f32x4){0.f, 0.f, 0.f, 0.f};

    const bf16x8* wf1v = (const bf16x8*)wf1;
#pragma unroll 4
    for (int ks = 0; ks < 16; ++ks) {
        bf16x8 bfr[4];
#pragma unroll
        for (int i = 0; i < 4; ++i)
            if (i < ntn) bfr[i] = wf1v[((ntl[i] * 16 + ks) << 6) + l];
        bf16x8 afr[2];
#pragma unroll
        for (int m = 0; m < 2; ++m)
            afr[m] = *(const bf16x8*)&xlds[(m * 16 + r) * 520 + ks * 32 + g * 8];
#pragma unroll
        for (int i = 0; i < 4; ++i)
            if (i < ntn)
#pragma unroll
                for (int m = 0; m < 2; ++m)
                    acc[i][m] = __builtin_amdgcn_mfma_f32_16x16x32_bf16(afr[m], bfr[i], acc[i][m], 0, 0, 0);
    }

    // epilogue 1: bias+relu -> h1 (bf16); gate logits -> gate
#pragma unroll
    for (int i = 0; i < 4; ++i)
        if (i < ntn) {
            int nt = ntl[i];
            if (nt < 24) {
#pragma unroll
                for (int m = 0; m < 2; ++m)
#pragma unroll
                    for (int q = 0; q < 4; ++q) {
                        int tokr = m * 16 + g * 4 + q;
                        int col = nt * 16 + r;
                        float v = acc[i][m][q] + b1c[col];
                        h1[tokr * 408 + col] = f2bf(fmaxf(v, 0.f));
                    }
            } else if (r < 8) {
#pragma unroll
                for (int m = 0; m < 2; ++m)
#pragma unroll
                    for (int q = 0; q < 4; ++q) {
                        int tokr = m * 16 + g * 4 + q;
                        gate[tokr * 8 + r] = acc[i][m][q] + b1c[384 + r];
                    }
            }
        }
    __syncthreads();

    // ---- phase 3: gate softmax (32 lanes) + layer-2 ----
    if (tid < 32) {
#pragma unroll
        for (int gi = 0; gi < 2; ++gi) {
            float l0 = gate[tid * 8 + gi * 4 + 0];
            float l1 = gate[tid * 8 + gi * 4 + 1];
            float l2 = gate[tid * 8 + gi * 4 + 2];
            float l3 = gate[tid * 8 + gi * 4 + 3];
            float mx = fmaxf(fmaxf(l0, l1), fmaxf(l2, l3));
            float e0 = __expf(l0 - mx), e1 = __expf(l1 - mx);
            float e2 = __expf(l2 - mx), e3 = __expf(l3 - mx);
            float inv = 1.f / (e0 + e1 + e2 + e3);
            sel[tid * 8 + gi * 4 + 0] = e0 * inv;
            sel[tid * 8 + gi * 4 + 1] = e1 * inv;
            sel[tid * 8 + gi * 4 + 2] = e2 * inv;
            sel[tid * 8 + gi * 4 + 3] = e3 * inv;
        }
    }

    // jobs: j in [0,12): e=j>>1, nt2=j&1. wave w -> job w; waves 0-3 also job w+8.
    const int nj = (w < 4) ? 2 : 1;
    const int je[2] = {w >> 1, (w + 8) >> 1};
    const int jn[2] = {w & 1, w & 1};

    f32x4 acc2[2][2];
#pragma unroll
    for (int jj = 0; jj < 2; ++jj)
#pragma unroll
        for (int m = 0; m < 2; ++m) acc2[jj][m] = (f32x4){0.f, 0.f, 0.f, 0.f};

    const bf16x8* wf2v = (const bf16x8*)wf2;
#pragma unroll
    for (int jj = 0; jj < 2; ++jj)
        if (jj < nj) {
            int e = je[jj], nt2 = jn[jj];
#pragma unroll
            for (int ks = 0; ks < 2; ++ks) {
                bf16x8 bb = wf2v[(((e * 2 + nt2) * 2 + ks) << 6) + l];
#pragma unroll
                for (int m = 0; m < 2; ++m) {
                    bf16x8 aa = *(const bf16x8*)&h1[(m * 16 + r) * 408 + e * 64 + ks * 32 + g * 8];
                    acc2[jj][m] = __builtin_amdgcn_mfma_f32_16x16x32_bf16(aa, bb, acc2[jj][m], 0, 0, 0);
                }
            }
        }
#pragma unroll
    for (int jj = 0; jj < 2; ++jj)
        if (jj < nj) {
            int e = je[jj], nt2 = jn[jj];
#pragma unroll
            for (int m = 0; m < 2; ++m)
#pragma unroll
                for (int q = 0; q < 4; ++q) {
                    int tokr = m * 16 + g * 4 + q;
                    int col = nt2 * 16 + r;
                    float v = acc2[jj][m][q] + b2c[e * 32 + col];
                    h2[tokr * 200 + e * 32 + col] = f2bf(fmaxf(v, 0.f));
                }
        }
    __syncthreads();

    // ---- phase 4: layer-3 -> eo (f32 [6][32][33], aliases h1; h1 dead) ----
    f32x4 acc3[2][2];
#pragma unroll
    for (int jj = 0; jj < 2; ++jj)
#pragma unroll
        for (int m = 0; m < 2; ++m) acc3[jj][m] = (f32x4){0.f, 0.f, 0.f, 0.f};

    const bf16x8* wf3v = (const bf16x8*)wf3;
#pragma unroll
    for (int jj = 0; jj < 2; ++jj)
        if (jj < nj) {
            int e = je[jj], nt2 = jn[jj];
            bf16x8 bb = wf3v[((e * 2 + nt2) << 6) + l];
#pragma unroll
            for (int m = 0; m < 2; ++m) {
                bf16x8 aa = *(const bf16x8*)&h2[(m * 16 + r) * 200 + e * 32 + g * 8];
                acc3[jj][m] = __builtin_amdgcn_mfma_f32_16x16x32_bf16(aa, bb, acc3[jj][m], 0, 0, 0);
            }
        }
#pragma unroll
    for (int jj = 0; jj < 2; ++jj)
        if (jj < nj) {
            int e = je[jj], nt2 = jn[jj];
#pragma unroll
            for (int m = 0; m < 2; ++m)
#pragma unroll
                for (int q = 0; q < 4; ++q) {
                    int tokr = m * 16 + g * 4 + q;
                    eo[(e * 32 + tokr) * 33 + nt2 * 16 + r] =
                        acc3[jj][m][q] + b3c[e * 32 + nt2 * 16 + r];
                }
        }
    __syncthreads();

    // ---- phase 5: gated mixing -> g1l, g2l (512 thr: 32 tok x 16 lanes x 2 cols) ----
    {
        int tok = tid >> 4, c0 = (tid & 15) * 2;
        float s[8];
#pragma unroll
        for (int i = 0; i < 8; ++i) s[i] = sel[tok * 8 + i];
#pragma unroll
        for (int c = 0; c < 2; ++c) {
            int cc = c0 + c;
            float e0 = eo[(0 * 32 + tok) * 33 + cc];
            float e1 = eo[(1 * 32 + tok) * 33 + cc];
            float e2 = eo[(2 * 32 + tok) * 33 + cc];
            float e3 = eo[(3 * 32 + tok) * 33 + cc];
            float e4 = eo[(4 * 32 + tok) * 33 + cc];
            float e5 = eo[(5 * 32 + tok) * 33 + cc];
            // task1 mix: [t1_0, t1_1, sh_0, sh_1] ; task2: [t2_0, t2_1, sh_0, sh_1]
            g1l[tok * 33 + cc] = s[0] * e0 + s[1] * e1 + s[2] * e4 + s[3] * e5;
            g2l[tok * 33 + cc] = s[4] * e2 + s[5] * e3 + s[6] * e4 + s[7] * e5;
        }
    }
    __syncthreads();

    // ---- phase 6: tower hidden (thr 0-255: tower1, 256-511: tower2) ----
    {
        int t = tid & 255, tower = tid >> 8;
        int tok = t >> 3, h0 = (t & 7) * 8;
        const float* W1 = tower ? tw2_W1 : tw1_W1;
        const float* B1 = tower ? tw2_b1 : tw1_b1;
        const float* gl = tower ? g2l : g1l;
        float* th = tower ? th2 : th1;
        float a[8];
#pragma unroll
        for (int hh = 0; hh < 8; ++hh) a[hh] = B1[h0 + hh];
        for (int c = 0; c < 32; ++c) {
            float gv = gl[tok * 33 + c];
#pragma unroll
            for (int hh = 0; hh < 8; ++hh)
                a[hh] += gv * W1[c * 64 + h0 + hh];
        }
#pragma unroll
        for (int hh = 0; hh < 8; ++hh)
            th[tok * 66 + h0 + hh] = fmaxf(a[hh], 0.f);
    }
    __syncthreads();

    // ---- phase 7: tower outputs ----
    if (tid < 128) {
        int tok = tid >> 2, jx = tid & 3;
        if (jx < 3) {
            float s = tw1_b2[jx];
            for (int hh = 0; hh < 64; ++hh) s += th1[tok * 66 + hh] * tw1_W2[hh * 3 + jx];
            if (jx != 1) s = 1.f / (1.f + __expf(-s));       // sigmoid cols 0,2
            out[(size_t)(tok0 + tok) * 3 + jx] = s;
        }
    } else if (tid >= 256 && tid < 384) {
        int t = tid - 256, tok = t >> 2, jx = t & 3;
        if (jx < 2) {
            float s = tw2_b2[jx];
            for (int hh = 0; hh < 64; ++hh) s += th2[tok * 66 + hh] * tw2_W2[hh * 2 + jx];
            if (jx == 1) s = 1.f / (1.f + __expf(-s));       // sigmoid col 1
            out[(size_t)ntok * 3 + (size_t)(tok0 + tok) * 2 + jx] = s;
        }
    }
}

// ---------------- launcher ----------------
extern "C" void kernel_launch(void* const* d_in, const int* in_sizes, int n_in,
                              void* d_out, int out_size, void* d_ws, size_t ws_size,
                              hipStream_t stream) {
    const float* x = (const float*)d_in[0];
    const float* sh_W1 = (const float*)d_in[1];
    const float* sh_b1 = (const float*)d_in[2];
    const float* sh_W2 = (const float*)d_in[3];
    const float* sh_b2 = (const float*)d_in[4];
    const float* sh_W3 = (const float*)d_in[5];
    const float* sh_b3 = (const float*)d_in[6];
    const float* t1_W1 = (const float*)d_in[7];
    const float* t1_b1 = (const float*)d_in[8];
    const float* t1_W2 = (const float*)d_in[9];
    const float* t1_b2 = (const float*)d_in[10];
    const float* t1_W3 = (const float*)d_in[11];
    const float* t1_b3 = (const float*)d_in[12];
    const float* t2_W1 = (const float*)d_in[13];
    const float* t2_b1 = (const float*)d_in[14];
    const float* t2_W2 = (const float*)d_in[15];
    const float* t2_b2 = (const float*)d_in[16];
    const float* t2_W3 = (const float*)d_in[17];
    const float* t2_b3 = (const float*)d_in[18];
    const float* g1_W = (const float*)d_in[19];
    const float* g1_b = (const float*)d_in[20];
    const float* g2_W = (const float*)d_in[21];
    const float* g2_b = (const float*)d_in[22];
    const float* tw1_W1 = (const float*)d_in[23];
    const float* tw1_b1 = (const float*)d_in[24];
    const float* tw1_W2 = (const float*)d_in[25];
    const float* tw1_b2 = (const float*)d_in[26];
    const float* tw2_W1 = (const float*)d_in[27];
    const float* tw2_b1 = (const float*)d_in[28];
    const float* tw2_W2 = (const float*)d_in[29];
    const float* tw2_b2 = (const float*)d_in[30];

    // d_ws layout (bytes): wf1@0 (409600), wf2@409600 (24576), wf3@434176 (12288),
    //                      b1c@446464 (1568), b2c@448032 (768), b3c@448800 (768)
    unsigned short* wf1 = (unsigned short*)d_ws;
    unsigned short* wf2 = (unsigned short*)((char*)d_ws + 409600);
    unsigned short* wf3 = (unsigned short*)((char*)d_ws + 434176);
    float* b1c = (float*)((char*)d_ws + 446464);
    float* b2c = (float*)((char*)d_ws + 448032);
    float* b3c = (float*)((char*)d_ws + 448800);

    pack_all<<<438, 512, 0, stream>>>(sh_W1, t1_W1, t2_W1, g1_W, g2_W,
                                      sh_W2, t1_W2, t2_W2, sh_W3, t1_W3, t2_W3,
                                      sh_b1, t1_b1, t2_b1, sh_b2, t1_b2, t2_b2,
                                      sh_b3, t1_b3, t2_b3, g1_b, g2_b,
                                      wf1, wf2, wf3, b1c, b2c, b3c);

    (void)hipFuncSetAttribute((const void*)ple_fused,
                              hipFuncAttributeMaxDynamicSharedMemorySize, LDS_BYTES);

    int ntok = in_sizes[0] / 512;
    int nblk = ntok / MT;
    ple_fused<<<nblk, 512, LDS_BYTES, stream>>>(
        x, wf1, wf2, wf3, b1c, b2c, b3c,
        tw1_W1, tw1_b1, tw1_W2, tw1_b2, tw2_W1, tw2_b1, tw2_W2, tw2_b2,
        (float*)d_out, ntok);
}